// Round 1
// baseline (413.290 us; speedup 1.0000x reference)
//
#include <hip/hip_runtime.h>

// LJ pair energy, fused edge->molecule scatter. 4 edges per lane per iter.
// R_EQ=1, WELL_DEPTH=1, CUTOFF=2.5, HEAL=0.5.
#define RCUT2  6.25f    // CUTOFF^2
#define RIN2   4.0f     // (CUTOFF-HEAL)^2
#define BT     512
#define NB     1024     // grid blocks for lj kernel (4/CU at BT=512)
#define RB     256      // reduce kernel block size
#define RCHUNK 8        // row-chunks in reduce kernel

// zero out[] and init uniform-flag
__global__ __launch_bounds__(256) void init_k(float* __restrict__ out, int n_mol,
                                              int* __restrict__ flag, int flag_init) {
    int i = blockIdx.x * 256 + threadIdx.x;
    if (i < n_mol) out[i] = 0.0f;
    if (i == 0) *flag = flag_init;
}

// Build molecule start offsets from sorted idx_m; verify idx_m matches the
// uniform formula (a*n_mol)/n_atoms (u64 div = ground truth).
__global__ __launch_bounds__(256) void build_bounds(
    const int* __restrict__ idx_m, int* __restrict__ start,
    int* __restrict__ flag, int n_atoms, int n_mol) {
    int a = blockIdx.x * 256 + threadIdx.x;
    if (a >= n_atoms) return;
    int m  = idx_m[a];
    int pm = (a == 0) ? -1 : idx_m[a - 1];
    for (int mm = pm + 1; mm <= m; ++mm) start[mm] = a;
    if (a == n_atoms - 1)
        for (int mm = m + 1; mm <= n_mol; ++mm) start[mm] = n_atoms;
    int mf = (int)(((unsigned long long)(unsigned)a * (unsigned)n_mol) / (unsigned)n_atoms);
    if (m != mf) atomicAnd(flag, 0);
}

// Main kernel: 4 edges per lane per grid-stride iteration.
// use_partial=1: flush per-block bins to partial[block][mol] (no atomics).
// use_partial=0: legacy rotated global-atomic flush directly into out.
__global__ __launch_bounds__(BT) void lj_direct4(
    const float* __restrict__ vec,      // [E][3] fp32, 16B-aligned base
    const int*   __restrict__ idx_i,
    const int*   __restrict__ bounds_g, // n_mol+1 (global; fallback only)
    const int*   __restrict__ flag,
    float*       __restrict__ dest,     // partial[NB][n_mol]  OR  out[n_mol]
    int n_edges, int n_mol,
    unsigned long long M, int sh, int use_partial)
{
    extern __shared__ float bins[];     // n_mol fp32
    for (int i = threadIdx.x; i < n_mol; i += BT) bins[i] = 0.0f;
    const bool uni = (*flag != 0);      // wave-uniform
    __syncthreads();

    auto body = [&](float vx, float vy, float vz, int a) {
        float r2 = fmaf(vx, vx, fmaf(vy, vy, vz * vz));
        if (r2 > RCUT2) return;         // switch == 0 exactly
        float inv2 = __builtin_amdgcn_rcpf(r2);     // v_rcp_f32 (tol >> 1 ulp)
        float p6   = inv2 * inv2 * inv2;
        float y    = fmaf(p6, p6, -p6); // p12 - p6
        // switch (branchless): t = 2r - 4, sw = 1 + t^2 (2t - 3)
        float r  = __builtin_amdgcn_sqrtf(r2);
        float t  = fmaf(2.0f, r, -4.0f);
        float sw = fmaf(t * t, fmaf(2.0f, t, -3.0f), 1.0f);
        y *= (r2 > RIN2) ? sw : 1.0f;
        // molecule of atom a: magic-multiply divide (host-verified exact)
        unsigned q = (unsigned)a * (unsigned)n_mol;
        int m = (int)(((unsigned long long)q * M) >> sh);
        if (!uni) {                     // general sorted-idx_m fallback
            if (m > n_mol - 1) m = n_mol - 1;
            if (m < 0) m = 0;
            while (m > 0 && a < bounds_g[m]) --m;
            while (m < n_mol - 1 && a >= bounds_g[m + 1]) ++m;
        }
        atomicAdd(&bins[m], y);
    };

    const float4* __restrict__ vec4 = (const float4*)vec;
    const int4*   __restrict__ idx4 = (const int4*)idx_i;
    const int ng     = n_edges >> 2;    // 4-edge groups
    const int stride = gridDim.x * BT;

    for (int g = blockIdx.x * BT + threadIdx.x; g < ng; g += stride) {
        // 3 x float4 = 12 floats = 4 edges; 1 x int4 = 4 atom ids. All 16B-aligned.
        float4 va = vec4[3 * g + 0];
        float4 vb = vec4[3 * g + 1];
        float4 vc = vec4[3 * g + 2];
        int4   ia = idx4[g];
        body(va.x, va.y, va.z, ia.x);
        body(va.w, vb.x, vb.y, ia.y);
        body(vb.z, vb.w, vc.x, ia.z);
        body(vc.y, vc.z, vc.w, ia.w);
    }

    // scalar tail (n_edges % 4 edges), handled by block 0
    const int tail = n_edges & 3;
    if (blockIdx.x == 0 && (int)threadIdx.x < tail) {
        int e = (ng << 2) + (int)threadIdx.x;
        body(vec[3 * e + 0], vec[3 * e + 1], vec[3 * e + 2], idx_i[e]);
    }

    __syncthreads();
    if (use_partial) {
        // plain coalesced stores of this block's bins; no atomics
        float* myp = dest + (size_t)blockIdx.x * (size_t)n_mol;
        for (int i = threadIdx.x; i < n_mol; i += BT) myp[i] = bins[i];
    } else {
        // legacy: rotated flush spreads global-atomic contention across bins
        unsigned off = (blockIdx.x * 131u) % (unsigned)n_mol;
        for (int i = threadIdx.x; i < n_mol; i += BT) {
            int j = i + (int)off; if (j >= n_mol) j -= n_mol;
            float bv = bins[j];
            if (bv != 0.0f) atomicAdd(&dest[j], 0.5f * bv);  // WELL_DEPTH * 0.5
        }
    }
}

// Sum partial[NB][n_mol] into out[n_mol]. Grid = colblocks * RCHUNK.
// Each block sums a 128-row x 256-col slab; rows are read coalesced (1 KB).
__global__ __launch_bounds__(RB) void reduce_k(
    const float* __restrict__ partial, float* __restrict__ out,
    int n_mol, int nb)
{
    const int colblocks = (n_mol + RB - 1) / RB;
    const int cb = blockIdx.x % colblocks;
    const int ch = blockIdx.x / colblocks;
    const int j  = cb * RB + (int)threadIdx.x;
    if (j >= n_mol) return;
    const int rows = nb / RCHUNK;
    const int b0 = ch * rows, b1 = b0 + rows;
    float s = 0.0f;
    #pragma unroll 4
    for (int b = b0; b < b1; ++b) s += partial[(size_t)b * (size_t)n_mol + j];
    atomicAdd(&out[j], 0.5f * s);       // WELL_DEPTH * 0.5; only RCHUNK atomics/mol
}

extern "C" void kernel_launch(void* const* d_in, const int* in_sizes, int n_in,
                              void* d_out, int out_size, void* d_ws, size_t ws_size,
                              hipStream_t stream) {
    const float* vec   = (const float*)d_in[0];
    const int*   idx_i = (const int*)d_in[2];
    const int*   idx_m = (const int*)d_in[3];
    float*       out   = (float*)d_out;

    const int n_edges = in_sizes[2];
    const int n_atoms = in_sizes[3];
    const int n_mol   = out_size;

    // workspace layout: [partial NB*n_mol fp32][start n_mol+1][flag]
    const size_t partial_bytes = (size_t)NB * (size_t)n_mol * sizeof(float);
    const size_t need = partial_bytes + (size_t)(n_mol + 2) * sizeof(int);
    const int use_partial = (ws_size >= need) ? 1 : 0;

    float* partial;
    int*   start;
    if (use_partial) {
        partial = (float*)d_ws;
        start   = (int*)(partial + (size_t)NB * (size_t)n_mol);
    } else {
        partial = nullptr;
        start   = (int*)d_ws;
    }
    int* flag = start + (n_mol + 1);

    // magic divisor for q/n_atoms, q = a*n_mol < 2^31:
    // M = 2^sh/d + 1; exact for all q < 2^31 iff M*d - 2^sh <= 2^(sh-31)
    unsigned d = (unsigned)n_atoms;
    unsigned long long M = 1; int sh = 32;
    bool ok = ((unsigned long long)(unsigned)n_mol * d) <= 0x7fffffffull;
    if (ok) {
        bool found = false;
        for (sh = 32; sh <= 62; ++sh) {
            unsigned long long tk = 1ull << sh;
            M = tk / d + 1;
            unsigned long long e = M * d - tk;
            if (e <= (1ull << (sh - 31))) { found = true; break; }
        }
        ok = found;
    }
    if (!ok) { M = 0; sh = 0; }               // forces fallback path

    init_k<<<(n_mol + 255) / 256, 256, 0, stream>>>(out, n_mol, flag, ok ? 1 : 0);
    build_bounds<<<(n_atoms + 255) / 256, 256, 0, stream>>>(idx_m, start, flag, n_atoms, n_mol);

    const size_t lds = (size_t)n_mol * sizeof(float);
    lj_direct4<<<NB, BT, lds, stream>>>(
        vec, idx_i, start, flag,
        use_partial ? partial : out,
        n_edges, n_mol, M, sh, use_partial);

    if (use_partial) {
        const int colblocks = (n_mol + RB - 1) / RB;
        reduce_k<<<colblocks * RCHUNK, RB, 0, stream>>>(partial, out, n_mol, NB);
    }
}

// Round 2
// 411.958 us; speedup vs baseline: 1.0032x; 1.0032x over previous
//
#include <hip/hip_runtime.h>

// LJ pair energy, fused edge->molecule scatter, LDS-staged coalesced loads.
// R_EQ=1, WELL_DEPTH=1, CUTOFF=2.5, HEAL=0.5.
#define RCUT2  6.25f    // CUTOFF^2
#define RIN2   4.0f     // (CUTOFF-HEAL)^2
#define BT     512      // threads per block (8 waves)
#define EPT    4        // edges per thread per tile
#define TILE   (BT*EPT)         // 2048 edges per tile
#define VTB    (TILE*12)        // 24576 B of vec per tile
#define WSB    (VTB/8)          // 3072 B staged per wave (3 x 64x16B ops)
#define NB     768              // 3 blocks/CU at ~52KB LDS
#define RB     256              // reduce kernel block size
#define RCHUNK 8                // row-chunks in reduce kernel

// ---------------- small kernels ----------------

__global__ __launch_bounds__(256) void init_k(float* __restrict__ out, int n_mol,
                                              int* __restrict__ flag, int flag_init) {
    int i = blockIdx.x * 256 + threadIdx.x;
    if (i < n_mol) out[i] = 0.0f;
    if (i == 0) *flag = flag_init;
}

// Build molecule start offsets from sorted idx_m; verify idx_m matches the
// uniform formula (a*n_mol)/n_atoms (u64 div = ground truth).
__global__ __launch_bounds__(256) void build_bounds(
    const int* __restrict__ idx_m, int* __restrict__ start,
    int* __restrict__ flag, int n_atoms, int n_mol) {
    int a = blockIdx.x * 256 + threadIdx.x;
    if (a >= n_atoms) return;
    int m  = idx_m[a];
    int pm = (a == 0) ? -1 : idx_m[a - 1];
    for (int mm = pm + 1; mm <= m; ++mm) start[mm] = a;
    if (a == n_atoms - 1)
        for (int mm = m + 1; mm <= n_mol; ++mm) start[mm] = n_atoms;
    int mf = (int)(((unsigned long long)(unsigned)a * (unsigned)n_mol) / (unsigned)n_atoms);
    if (m != mf) atomicAnd(flag, 0);
}

// ---------------- per-edge physics ----------------

__device__ __forceinline__ void lj_body(
    float vx, float vy, float vz, int a,
    bool uni, const int* __restrict__ bounds_g, float* bins,
    int n_mol, unsigned long long M, int sh)
{
    float r2 = fmaf(vx, vx, fmaf(vy, vy, vz * vz));
    if (r2 > RCUT2) return;             // switch == 0 exactly
    float inv2 = __builtin_amdgcn_rcpf(r2);     // v_rcp_f32 (tol >> 1 ulp)
    float p6   = inv2 * inv2 * inv2;
    float y    = fmaf(p6, p6, -p6);     // p12 - p6
    // switch (branchless): t = 2r - 4, sw = 1 + t^2 (2t - 3)
    float r  = __builtin_amdgcn_sqrtf(r2);
    float t  = fmaf(2.0f, r, -4.0f);
    float sw = fmaf(t * t, fmaf(2.0f, t, -3.0f), 1.0f);
    y *= (r2 > RIN2) ? sw : 1.0f;
    // molecule of atom a: magic-multiply divide (host-verified exact)
    unsigned q = (unsigned)a * (unsigned)n_mol;
    int m = (int)(((unsigned long long)q * M) >> sh);
    if (!uni) {                         // general sorted-idx_m fallback
        if (m > n_mol - 1) m = n_mol - 1;
        if (m < 0) m = 0;
        while (m > 0 && a < bounds_g[m]) --m;
        while (m < n_mol - 1 && a >= bounds_g[m + 1]) ++m;
    }
    atomicAdd(&bins[m], y);
}

// async 16B/lane global->LDS (wave-uniform LDS base + lane*16, per-lane global)
__device__ __forceinline__ void gload_lds16(const void* g, void* l) {
    __builtin_amdgcn_global_load_lds(
        (__attribute__((address_space(1))) void*)g,
        (__attribute__((address_space(3))) void*)l,
        16, 0, 0);
}

// ---------------- main kernel: LDS-staged, double-buffered ----------------
// LDS layout: [bins n_mol fp32 (padded to bins_pad)] [buf0 VTB] [buf1 VTB]

__global__ __launch_bounds__(BT) void lj_staged(
    const float* __restrict__ vec,      // [E][3] fp32
    const int*   __restrict__ idx_i,
    const int*   __restrict__ bounds_g,
    const int*   __restrict__ flag,
    float*       __restrict__ dest,     // partial[NB][n_mol] OR out[n_mol]
    int n_edges, int n_mol, int bins_pad,
    unsigned long long M, int sh, int use_partial)
{
    extern __shared__ char smem[];
    float* bins = (float*)smem;
    char* sb0 = smem + bins_pad;
    char* sb1 = sb0 + VTB;
    for (int i = threadIdx.x; i < n_mol; i += BT) bins[i] = 0.0f;
    const bool uni = (*flag != 0);      // wave-uniform

    const int ntiles = n_edges / TILE;
    const int gdim   = (int)gridDim.x;
    const char* vecb = (const char*)vec;
    const int w    = threadIdx.x >> 6;  // wave id, uniform per wave
    const int lane = threadIdx.x & 63;

    // prologue: stage first tile into buf0
    if ((int)blockIdx.x < ntiles) {
        const char* g = vecb + (size_t)blockIdx.x * VTB + (size_t)(w * WSB + lane * 16);
        char* l = sb0 + w * WSB;
        #pragma unroll
        for (int op = 0; op < 3; ++op)
            gload_lds16(g + op * 1024, l + op * 1024);
    }

    int cur = 0;
    for (int t = blockIdx.x; t < ntiles; t += gdim) {
        __syncthreads();                // drains vmcnt -> stage(cur) landed; joins waves

        int tn = t + gdim;              // issue next-tile stage into other buffer
        if (tn < ntiles) {
            const char* g = vecb + (size_t)tn * VTB + (size_t)(w * WSB + lane * 16);
            char* l = (cur ? sb0 : sb1) + w * WSB;
            #pragma unroll
            for (int op = 0; op < 3; ++op)
                gload_lds16(g + op * 1024, l + op * 1024);
        }

        // compute current tile from LDS; edges lane-strided so idx loads coalesce
        const float* vb = (const float*)(cur ? sb1 : sb0);
        const size_t eb = (size_t)t * TILE;
        const int l0 = threadIdx.x;
        int a0 = idx_i[eb + l0];
        int a1 = idx_i[eb + l0 + BT];
        int a2 = idx_i[eb + l0 + 2 * BT];
        int a3 = idx_i[eb + l0 + 3 * BT];
        // word addr 3*e: gcd(3,32)=1 -> conflict-free LDS banks
        float x0 = vb[3 * l0 + 0],            y0 = vb[3 * l0 + 1],            z0 = vb[3 * l0 + 2];
        float x1 = vb[3 * (l0 + BT) + 0],     y1 = vb[3 * (l0 + BT) + 1],     z1 = vb[3 * (l0 + BT) + 2];
        float x2 = vb[3 * (l0 + 2 * BT) + 0], y2 = vb[3 * (l0 + 2 * BT) + 1], z2 = vb[3 * (l0 + 2 * BT) + 2];
        float x3 = vb[3 * (l0 + 3 * BT) + 0], y3 = vb[3 * (l0 + 3 * BT) + 1], z3 = vb[3 * (l0 + 3 * BT) + 2];
        lj_body(x0, y0, z0, a0, uni, bounds_g, bins, n_mol, M, sh);
        lj_body(x1, y1, z1, a1, uni, bounds_g, bins, n_mol, M, sh);
        lj_body(x2, y2, z2, a2, uni, bounds_g, bins, n_mol, M, sh);
        lj_body(x3, y3, z3, a3, uni, bounds_g, bins, n_mol, M, sh);
        cur ^= 1;
    }

    // tail edges (n_edges % TILE), block 0, guarded scalar loads
    if (blockIdx.x == 0) {
        for (int e = ntiles * TILE + (int)threadIdx.x; e < n_edges; e += BT) {
            size_t b = 3 * (size_t)e;
            lj_body(vec[b], vec[b + 1], vec[b + 2], idx_i[e],
                    uni, bounds_g, bins, n_mol, M, sh);
        }
    }

    __syncthreads();
    if (use_partial) {                  // plain coalesced stores; no atomics
        float* myp = dest + (size_t)blockIdx.x * (size_t)n_mol;
        for (int i = threadIdx.x; i < n_mol; i += BT) myp[i] = bins[i];
    } else {                            // rotated atomic flush fallback
        unsigned off = (blockIdx.x * 131u) % (unsigned)n_mol;
        for (int i = threadIdx.x; i < n_mol; i += BT) {
            int j = i + (int)off; if (j >= n_mol) j -= n_mol;
            float bv = bins[j];
            if (bv != 0.0f) atomicAdd(&dest[j], 0.5f * bv);
        }
    }
}

// fallback (LDS budget exceeded): scalar per-edge loads, same flush options
__global__ __launch_bounds__(BT) void lj_fallback(
    const float* __restrict__ vec, const int* __restrict__ idx_i,
    const int* __restrict__ bounds_g, const int* __restrict__ flag,
    float* __restrict__ dest, int n_edges, int n_mol,
    unsigned long long M, int sh, int use_partial)
{
    extern __shared__ float bins[];
    for (int i = threadIdx.x; i < n_mol; i += BT) bins[i] = 0.0f;
    const bool uni = (*flag != 0);
    __syncthreads();
    const int stride = gridDim.x * BT;
    for (int e = blockIdx.x * BT + threadIdx.x; e < n_edges; e += stride) {
        size_t b = 3 * (size_t)e;
        lj_body(vec[b], vec[b + 1], vec[b + 2], idx_i[e],
                uni, bounds_g, bins, n_mol, M, sh);
    }
    __syncthreads();
    if (use_partial) {
        float* myp = dest + (size_t)blockIdx.x * (size_t)n_mol;
        for (int i = threadIdx.x; i < n_mol; i += BT) myp[i] = bins[i];
    } else {
        unsigned off = (blockIdx.x * 131u) % (unsigned)n_mol;
        for (int i = threadIdx.x; i < n_mol; i += BT) {
            int j = i + (int)off; if (j >= n_mol) j -= n_mol;
            float bv = bins[j];
            if (bv != 0.0f) atomicAdd(&dest[j], 0.5f * bv);
        }
    }
}

// Sum partial[nb][n_mol] into out[n_mol]; rows read coalesced.
__global__ __launch_bounds__(RB) void reduce_k(
    const float* __restrict__ partial, float* __restrict__ out,
    int n_mol, int nb)
{
    const int colblocks = (n_mol + RB - 1) / RB;
    const int cb = blockIdx.x % colblocks;
    const int ch = blockIdx.x / colblocks;
    const int j  = cb * RB + (int)threadIdx.x;
    if (j >= n_mol) return;
    const int rows = nb / RCHUNK;
    const int b0 = ch * rows, b1 = b0 + rows;
    float s = 0.0f;
    #pragma unroll 4
    for (int b = b0; b < b1; ++b) s += partial[(size_t)b * (size_t)n_mol + j];
    atomicAdd(&out[j], 0.5f * s);       // WELL_DEPTH * 0.5
}

// ---------------- host ----------------

extern "C" void kernel_launch(void* const* d_in, const int* in_sizes, int n_in,
                              void* d_out, int out_size, void* d_ws, size_t ws_size,
                              hipStream_t stream) {
    const float* vec   = (const float*)d_in[0];
    const int*   idx_i = (const int*)d_in[2];
    const int*   idx_m = (const int*)d_in[3];
    float*       out   = (float*)d_out;

    const int n_edges = in_sizes[2];
    const int n_atoms = in_sizes[3];
    const int n_mol   = out_size;

    // workspace layout: [partial NB*n_mol fp32][start n_mol+1][flag]
    const size_t partial_bytes = (size_t)NB * (size_t)n_mol * sizeof(float);
    const size_t need = partial_bytes + (size_t)(n_mol + 2) * sizeof(int);
    const int use_partial = (ws_size >= need) ? 1 : 0;

    float* partial;
    int*   start;
    if (use_partial) {
        partial = (float*)d_ws;
        start   = (int*)(partial + (size_t)NB * (size_t)n_mol);
    } else {
        partial = nullptr;
        start   = (int*)d_ws;
    }
    int* flag = start + (n_mol + 1);

    // magic divisor for q/n_atoms, q = a*n_mol < 2^31:
    // M = 2^sh/d + 1; exact for all q < 2^31 iff M*d - 2^sh <= 2^(sh-31)
    unsigned d = (unsigned)n_atoms;
    unsigned long long M = 1; int sh = 32;
    bool ok = ((unsigned long long)(unsigned)n_mol * d) <= 0x7fffffffull;
    if (ok) {
        bool found = false;
        for (sh = 32; sh <= 62; ++sh) {
            unsigned long long tk = 1ull << sh;
            M = tk / d + 1;
            unsigned long long e = M * d - tk;
            if (e <= (1ull << (sh - 31))) { found = true; break; }
        }
        ok = found;
    }
    if (!ok) { M = 0; sh = 0; }         // forces fallback walk

    init_k<<<(n_mol + 255) / 256, 256, 0, stream>>>(out, n_mol, flag, ok ? 1 : 0);
    build_bounds<<<(n_atoms + 255) / 256, 256, 0, stream>>>(idx_m, start, flag, n_atoms, n_mol);

    const int    bins_pad = (n_mol * 4 + 255) & ~255;
    const size_t lds_staged = (size_t)bins_pad + 2 * VTB;

    if (lds_staged <= 64 * 1024) {
        lj_staged<<<NB, BT, lds_staged, stream>>>(
            vec, idx_i, start, flag,
            use_partial ? partial : out,
            n_edges, n_mol, bins_pad, M, sh, use_partial);
    } else {
        lj_fallback<<<NB, BT, (size_t)n_mol * sizeof(float), stream>>>(
            vec, idx_i, start, flag,
            use_partial ? partial : out,
            n_edges, n_mol, M, sh, use_partial);
    }

    if (use_partial) {
        const int colblocks = (n_mol + RB - 1) / RB;
        reduce_k<<<colblocks * RCHUNK, RB, 0, stream>>>(partial, out, n_mol, NB);
    }
}

// Round 3
// 410.776 us; speedup vs baseline: 1.0061x; 1.0029x over previous
//
#include <hip/hip_runtime.h>

// LJ pair energy, fused edge->molecule scatter.
// LDS-staged coalesced vec loads + direct rotated-atomic flush (no reduce pass).
// R_EQ=1, WELL_DEPTH=1, CUTOFF=2.5, HEAL=0.5.
#define RCUT2  6.25f    // CUTOFF^2
#define RIN2   4.0f     // (CUTOFF-HEAL)^2
#define BT     512      // threads per block (8 waves)
#define EPT    4        // edges per thread per tile
#define TILE   (BT*EPT)         // 2048 edges per tile
#define VTB    (TILE*12)        // 24576 B of vec per tile
#define WSB    (VTB/8)          // 3072 B staged per wave (3 x 64-lane x 16B)
#define NB     768              // exactly 3 blocks/CU at ~52KB LDS

// ---------------- small kernels ----------------

__global__ __launch_bounds__(256) void init_k(float* __restrict__ out, int n_mol,
                                              int* __restrict__ flag, int flag_init) {
    int i = blockIdx.x * 256 + threadIdx.x;
    if (i < n_mol) out[i] = 0.0f;
    if (i == 0) *flag = flag_init;
}

// Build molecule start offsets from sorted idx_m; verify idx_m matches the
// uniform formula (a*n_mol)/n_atoms (u64 div = ground truth).
__global__ __launch_bounds__(256) void build_bounds(
    const int* __restrict__ idx_m, int* __restrict__ start,
    int* __restrict__ flag, int n_atoms, int n_mol) {
    int a = blockIdx.x * 256 + threadIdx.x;
    if (a >= n_atoms) return;
    int m  = idx_m[a];
    int pm = (a == 0) ? -1 : idx_m[a - 1];
    for (int mm = pm + 1; mm <= m; ++mm) start[mm] = a;
    if (a == n_atoms - 1)
        for (int mm = m + 1; mm <= n_mol; ++mm) start[mm] = n_atoms;
    int mf = (int)(((unsigned long long)(unsigned)a * (unsigned)n_mol) / (unsigned)n_atoms);
    if (m != mf) atomicAnd(flag, 0);
}

// ---------------- per-edge physics ----------------

__device__ __forceinline__ void lj_body(
    float vx, float vy, float vz, int a,
    bool uni, const int* __restrict__ bounds_g, float* bins,
    int n_mol, unsigned long long M, int sh)
{
    float r2 = fmaf(vx, vx, fmaf(vy, vy, vz * vz));
    if (r2 > RCUT2) return;             // switch == 0 exactly
    float inv2 = __builtin_amdgcn_rcpf(r2);     // v_rcp_f32 (tol >> 1 ulp)
    float p6   = inv2 * inv2 * inv2;
    float y    = fmaf(p6, p6, -p6);     // p12 - p6
    // switch (branchless): t = 2r - 4, sw = 1 + t^2 (2t - 3)
    float r  = __builtin_amdgcn_sqrtf(r2);
    float t  = fmaf(2.0f, r, -4.0f);
    float sw = fmaf(t * t, fmaf(2.0f, t, -3.0f), 1.0f);
    y *= (r2 > RIN2) ? sw : 1.0f;
    // molecule of atom a: magic-multiply divide (host-verified exact)
    unsigned q = (unsigned)a * (unsigned)n_mol;
    int m = (int)(((unsigned long long)q * M) >> sh);
    if (!uni) {                         // general sorted-idx_m fallback
        if (m > n_mol - 1) m = n_mol - 1;
        if (m < 0) m = 0;
        while (m > 0 && a < bounds_g[m]) --m;
        while (m < n_mol - 1 && a >= bounds_g[m + 1]) ++m;
    }
    atomicAdd(&bins[m], y);
}

// async 16B/lane global->LDS (wave-uniform LDS base + lane*16, per-lane global)
__device__ __forceinline__ void gload_lds16(const void* g, void* l) {
    __builtin_amdgcn_global_load_lds(
        (__attribute__((address_space(1))) void*)g,
        (__attribute__((address_space(3))) void*)l,
        16, 0, 0);
}

// ---------------- main kernel ----------------
// LDS layout: [bins n_mol fp32 (padded)] [buf0 VTB] [buf1 VTB]
// Per tile: stage(next) via global_load_lds, int4 idx prefetch (1 tile ahead,
// latency hidden under compute), compute(cur) from LDS via 3x ds_read_b128.

__global__ __launch_bounds__(BT) void lj_staged(
    const float* __restrict__ vec,      // [E][3] fp32
    const int*   __restrict__ idx_i,
    const int*   __restrict__ bounds_g,
    const int*   __restrict__ flag,
    float*       __restrict__ out,
    int n_edges, int n_mol, int bins_pad,
    unsigned long long M, int sh)
{
    extern __shared__ char smem[];
    float* bins = (float*)smem;
    char* sb0 = smem + bins_pad;
    char* sb1 = sb0 + VTB;
    for (int i = threadIdx.x; i < n_mol; i += BT) bins[i] = 0.0f;
    const bool uni = (*flag != 0);      // wave-uniform

    const int ntiles = n_edges / TILE;
    const int gdim   = (int)gridDim.x;
    const int tid    = (int)threadIdx.x;
    const int w      = tid >> 6;        // wave id (uniform per wave)
    const int lane   = tid & 63;
    const char* vecb = (const char*)vec;
    const int4* idx4 = (const int4*)idx_i;

    // prologue: stage first tile into buf0, prefetch its idx quad
    int4 ia = make_int4(0, 0, 0, 0);
    const int t0 = (int)blockIdx.x;
    if (t0 < ntiles) {
        const char* g = vecb + (size_t)t0 * VTB + (size_t)(w * WSB + lane * 16);
        char* l = sb0 + w * WSB;
        #pragma unroll
        for (int op = 0; op < 3; ++op)
            gload_lds16(g + op * 1024, l + op * 1024);
        ia = idx4[(size_t)t0 * (TILE / 4) + tid];
    }

    int cur = 0;
    for (int t = t0; t < ntiles; t += gdim) {
        __syncthreads();                // drains vmcnt -> stage(cur)+ia landed

        int tn = t + gdim;              // issue next-tile stage + idx prefetch
        int4 ian = make_int4(0, 0, 0, 0);
        if (tn < ntiles) {
            const char* g = vecb + (size_t)tn * VTB + (size_t)(w * WSB + lane * 16);
            char* l = (cur ? sb0 : sb1) + w * WSB;
            #pragma unroll
            for (int op = 0; op < 3; ++op)
                gload_lds16(g + op * 1024, l + op * 1024);
            ian = idx4[(size_t)tn * (TILE / 4) + tid];
        }

        // compute current tile: thread owns edges 4*tid..4*tid+3 of the tile
        const float4* vb4 = (const float4*)(cur ? sb1 : sb0);
        float4 w0 = vb4[3 * tid + 0];   // 3x ds_read_b128, 48B/thread
        float4 w1 = vb4[3 * tid + 1];
        float4 w2 = vb4[3 * tid + 2];
        lj_body(w0.x, w0.y, w0.z, ia.x, uni, bounds_g, bins, n_mol, M, sh);
        lj_body(w0.w, w1.x, w1.y, ia.y, uni, bounds_g, bins, n_mol, M, sh);
        lj_body(w1.z, w1.w, w2.x, ia.z, uni, bounds_g, bins, n_mol, M, sh);
        lj_body(w2.y, w2.z, w2.w, ia.w, uni, bounds_g, bins, n_mol, M, sh);
        ia = ian;                       // waitcnt for prefetch lands here
        cur ^= 1;
    }

    // tail edges (n_edges % TILE), block 0, guarded scalar loads
    if (blockIdx.x == 0) {
        for (int e = ntiles * TILE + tid; e < n_edges; e += BT) {
            size_t b = 3 * (size_t)e;
            lj_body(vec[b], vec[b + 1], vec[b + 2], idx_i[e],
                    uni, bounds_g, bins, n_mol, M, sh);
        }
    }

    __syncthreads();
    // rotated flush spreads global-atomic contention across bins
    unsigned off = (blockIdx.x * 131u) % (unsigned)n_mol;
    for (int i = tid; i < n_mol; i += BT) {
        int j = i + (int)off; if (j >= n_mol) j -= n_mol;
        float bv = bins[j];
        if (bv != 0.0f) atomicAdd(&out[j], 0.5f * bv);   // WELL_DEPTH * 0.5
    }
}

// fallback (LDS budget exceeded): scalar per-edge loads, same flush
__global__ __launch_bounds__(BT) void lj_fallback(
    const float* __restrict__ vec, const int* __restrict__ idx_i,
    const int* __restrict__ bounds_g, const int* __restrict__ flag,
    float* __restrict__ out, int n_edges, int n_mol,
    unsigned long long M, int sh)
{
    extern __shared__ float bins[];
    for (int i = threadIdx.x; i < n_mol; i += BT) bins[i] = 0.0f;
    const bool uni = (*flag != 0);
    __syncthreads();
    const int stride = gridDim.x * BT;
    for (int e = blockIdx.x * BT + threadIdx.x; e < n_edges; e += stride) {
        size_t b = 3 * (size_t)e;
        lj_body(vec[b], vec[b + 1], vec[b + 2], idx_i[e],
                uni, bounds_g, bins, n_mol, M, sh);
    }
    __syncthreads();
    unsigned off = (blockIdx.x * 131u) % (unsigned)n_mol;
    for (int i = threadIdx.x; i < n_mol; i += BT) {
        int j = i + (int)off; if (j >= n_mol) j -= n_mol;
        float bv = bins[j];
        if (bv != 0.0f) atomicAdd(&out[j], 0.5f * bv);
    }
}

// ---------------- host ----------------

extern "C" void kernel_launch(void* const* d_in, const int* in_sizes, int n_in,
                              void* d_out, int out_size, void* d_ws, size_t ws_size,
                              hipStream_t stream) {
    const float* vec   = (const float*)d_in[0];
    const int*   idx_i = (const int*)d_in[2];
    const int*   idx_m = (const int*)d_in[3];
    float*       out   = (float*)d_out;

    const int n_edges = in_sizes[2];
    const int n_atoms = in_sizes[3];
    const int n_mol   = out_size;

    int* start = (int*)d_ws;                  // n_mol+1 ints
    int* flag  = (int*)d_ws + (n_mol + 2);    // 1 int

    // magic divisor for q/n_atoms, q = a*n_mol < 2^31:
    // M = 2^sh/d + 1; exact for all q < 2^31 iff M*d - 2^sh <= 2^(sh-31)
    unsigned d = (unsigned)n_atoms;
    unsigned long long M = 1; int sh = 32;
    bool ok = ((unsigned long long)(unsigned)n_mol * d) <= 0x7fffffffull;
    if (ok) {
        bool found = false;
        for (sh = 32; sh <= 62; ++sh) {
            unsigned long long tk = 1ull << sh;
            M = tk / d + 1;
            unsigned long long e = M * d - tk;
            if (e <= (1ull << (sh - 31))) { found = true; break; }
        }
        ok = found;
    }
    if (!ok) { M = 0; sh = 0; }               // forces fallback walk

    init_k<<<(n_mol + 255) / 256, 256, 0, stream>>>(out, n_mol, flag, ok ? 1 : 0);
    build_bounds<<<(n_atoms + 255) / 256, 256, 0, stream>>>(idx_m, start, flag, n_atoms, n_mol);

    const int    bins_pad   = (n_mol * 4 + 255) & ~255;
    const size_t lds_staged = (size_t)bins_pad + 2 * VTB;

    if (lds_staged <= 64 * 1024) {
        lj_staged<<<NB, BT, lds_staged, stream>>>(
            vec, idx_i, start, flag, out, n_edges, n_mol, bins_pad, M, sh);
    } else {
        lj_fallback<<<NB, BT, (size_t)n_mol * sizeof(float), stream>>>(
            vec, idx_i, start, flag, out, n_edges, n_mol, M, sh);
    }
}

// Round 4
// 400.892 us; speedup vs baseline: 1.0309x; 1.0247x over previous
//
#include <hip/hip_runtime.h>

// LJ pair energy, fused edge->molecule scatter. One lane = one edge.
// R_EQ=1, WELL_DEPTH=1, CUTOFF=2.5, HEAL=0.5.
//
// NOTE (session ledger): this is the empirically-best configuration (R0,
// 400.2 us; prior session 399.4 us). Rounds 1-3 tried partial-buffer
// two-stage reduction, float4 AoS loads, and global_load_lds double-buffered
// staging: lj's solo speed improved but total regressed 10-13 us in every
// case. rocprof shows lj co-runs with a 960 MB harness poison fill
// (fill 6.74 TB/s + lj 1.14 TB/s = 7.9 TB/s = HBM peak) -- lj is pinned to
// the fill window, and max-occupancy direct loads (4 blocks/CU, 32 waves/CU,
// 4 KB LDS) overlap that co-runner best.
#define RCUT2  6.25f    // CUTOFF^2
#define RIN2   4.0f     // (CUTOFF-HEAL)^2
#define BT     512

struct __attribute__((aligned(4))) F3 { float x, y, z; };   // 12 B, no padding

// zero out[] and init uniform-flag
__global__ __launch_bounds__(256) void init_k(float* __restrict__ out, int n_mol,
                                              int* __restrict__ flag, int flag_init) {
    int i = blockIdx.x * 256 + threadIdx.x;
    if (i < n_mol) out[i] = 0.0f;
    if (i == 0) *flag = flag_init;
}

// Build molecule start offsets from sorted idx_m; verify idx_m matches the
// uniform formula (a*n_mol)/n_atoms (u64 div = ground truth).
__global__ __launch_bounds__(256) void build_bounds(
    const int* __restrict__ idx_m, int* __restrict__ start,
    int* __restrict__ flag, int n_atoms, int n_mol) {
    int a = blockIdx.x * 256 + threadIdx.x;
    if (a >= n_atoms) return;
    int m  = idx_m[a];
    int pm = (a == 0) ? -1 : idx_m[a - 1];
    for (int mm = pm + 1; mm <= m; ++mm) start[mm] = a;
    if (a == n_atoms - 1)
        for (int mm = m + 1; mm <= n_mol; ++mm) start[mm] = n_atoms;
    int mf = (int)(((unsigned long long)(unsigned)a * (unsigned)n_mol) / (unsigned)n_atoms);
    if (m != mf) atomicAnd(flag, 0);
}

__global__ __launch_bounds__(BT) void lj_direct(
    const F3*  __restrict__ vec3,
    const int* __restrict__ idx_i,
    const int* __restrict__ bounds_g,   // n_mol+1 (global; fallback only)
    const int* __restrict__ flag,
    float*     __restrict__ out,
    int n_edges, int n_mol,
    unsigned long long M, int sh)
{
    extern __shared__ float bins[];     // n_mol fp32
    for (int i = threadIdx.x; i < n_mol; i += BT) bins[i] = 0.0f;
    const bool uni = (*flag != 0);      // wave-uniform
    __syncthreads();

    const int stride = gridDim.x * BT;
    for (int e = blockIdx.x * BT + threadIdx.x; e < n_edges; e += stride) {
        F3  v = vec3[e];                // 12 B/lane -> global_load_dwordx3
        int a = idx_i[e];               // 4 B/lane, coalesced

        float r2 = fmaf(v.x, v.x, fmaf(v.y, v.y, v.z * v.z));
        if (r2 > RCUT2) continue;       // switch == 0 exactly

        float inv2 = __builtin_amdgcn_rcpf(r2);     // v_rcp_f32 (tol >> 1 ulp)
        float p6   = inv2 * inv2 * inv2;
        float y    = fmaf(p6, p6, -p6); // p12 - p6

        // switch (branchless): t = 2r - 4, sw = 1 + t^2 (2t - 3)
        float r  = __builtin_amdgcn_sqrtf(r2);
        float t  = fmaf(2.0f, r, -4.0f);
        float sw = fmaf(t * t, fmaf(2.0f, t, -3.0f), 1.0f);
        y *= (r2 > RIN2) ? sw : 1.0f;

        // molecule of atom a: magic-multiply divide (host-verified exact)
        unsigned q = (unsigned)a * (unsigned)n_mol;
        int m = (int)(((unsigned long long)q * M) >> sh);
        if (!uni) {                     // general sorted-idx_m fallback
            if (m > n_mol - 1) m = n_mol - 1;
            if (m < 0) m = 0;
            while (m > 0 && a < bounds_g[m]) --m;
            while (m < n_mol - 1 && a >= bounds_g[m + 1]) ++m;
        }
        atomicAdd(&bins[m], y);
    }

    __syncthreads();
    // rotated flush spreads global-atomic contention across bins
    unsigned off = (blockIdx.x * 131u) % (unsigned)n_mol;
    for (int i = threadIdx.x; i < n_mol; i += BT) {
        int j = i + (int)off; if (j >= n_mol) j -= n_mol;
        float bv = bins[j];
        if (bv != 0.0f) atomicAdd(&out[j], 0.5f * bv);   // WELL_DEPTH * 0.5
    }
}

extern "C" void kernel_launch(void* const* d_in, const int* in_sizes, int n_in,
                              void* d_out, int out_size, void* d_ws, size_t ws_size,
                              hipStream_t stream) {
    const float* vec   = (const float*)d_in[0];
    const int*   idx_i = (const int*)d_in[2];
    const int*   idx_m = (const int*)d_in[3];
    float*       out   = (float*)d_out;

    const int n_edges = in_sizes[2];
    const int n_atoms = in_sizes[3];
    const int n_mol   = out_size;

    int* start = (int*)d_ws;                  // n_mol+1 ints
    int* flag  = (int*)d_ws + (n_mol + 2);    // 1 int

    // magic divisor for q/n_atoms, q = a*n_mol < 2^31:
    // M = 2^sh/d + 1; exact for all q < 2^31 iff M*d - 2^sh <= 2^(sh-31)
    unsigned d = (unsigned)n_atoms;
    unsigned long long M = 1; int sh = 32;
    bool ok = ((unsigned long long)(unsigned)n_mol * d) <= 0x7fffffffull;
    if (ok) {
        bool found = false;
        for (sh = 32; sh <= 62; ++sh) {
            unsigned long long tk = 1ull << sh;
            M = tk / d + 1;
            unsigned long long e = M * d - tk;
            if (e <= (1ull << (sh - 31))) { found = true; break; }
        }
        ok = found;
    }
    if (!ok) { M = 0; sh = 0; }               // forces fallback path

    init_k<<<(n_mol + 255) / 256, 256, 0, stream>>>(out, n_mol, flag, ok ? 1 : 0);
    build_bounds<<<(n_atoms + 255) / 256, 256, 0, stream>>>(idx_m, start, flag, n_atoms, n_mol);

    const int    nb  = 1024;                  // 4 blocks/CU x 512 = 32 waves/CU
    const size_t lds = (size_t)n_mol * sizeof(float);
    lj_direct<<<nb, BT, lds, stream>>>(
        (const F3*)vec, idx_i, start, flag, out, n_edges, n_mol, M, sh);
}